// Round 1
// baseline (299.414 us; speedup 1.0000x reference)
//
#include <hip/hip_runtime.h>
#include <math.h>

// LinearAttention: B=16, C=256, H=W=64 (N=4096), 8 heads x 32 dim.
// Pipeline: rnorm -> W'=w_qkv*g1 (bf16) -> MFMA GEMM qkv (bf16, rinv-scaled)
//  -> q-softmax in place -> partial sum(exp(k)*v), sum(exp(k)) over 4 n-slices
//  -> fold M = SCALE * w_out . ctx / sum  -> MFMA GEMM final + fused
//     (+b_out, RMSNorm*g2*16, +x) epilogue.
// Workspace: ~101 MiB.

#define B_ 16
#define C_ 256
#define N_ 4096
#define QKV_ 768
#define SCALE_ 0.17677669529663687f
#define EPS_ 1e-12f

typedef __attribute__((ext_vector_type(8))) short bf16x8;
typedef __attribute__((ext_vector_type(4))) float f32x4;

__device__ __forceinline__ ushort f2bf(float f) {
    union { float f; uint u; } x; x.f = f;
    uint r = (x.u + 0x7FFFu + ((x.u >> 16) & 1u)) >> 16;
    return (ushort)r;
}
__device__ __forceinline__ float bf2f(ushort s) {
    union { uint u; float f; } x; x.u = ((uint)s) << 16;
    return x.f;
}

// ---------------- K1: W' = w_qkv * g1 -> bf16 ----------------
__global__ __launch_bounds__(256) void k_prep(const float* __restrict__ w_qkv,
                                              const float* __restrict__ g1,
                                              ushort* __restrict__ Wp) {
    int o = blockIdx.x, c = threadIdx.x;
    Wp[(size_t)o * 256 + c] = f2bf(w_qkv[(size_t)o * 256 + c] * g1[c]);
}

// ---------------- K2: rinv[b,n] = 16 / max(||x[:,n]||, eps) ----------------
__global__ __launch_bounds__(256) void k_rnorm(const float* __restrict__ x,
                                               float* __restrict__ rinv) {
    int p = blockIdx.x * 256 + threadIdx.x;
    int b = p >> 12, n = p & 4095;
    const float* xb = x + (size_t)b * C_ * N_ + n;
    float ss = 0.f;
    #pragma unroll 8
    for (int c = 0; c < 256; ++c) { float v = xb[(size_t)c * N_]; ss += v * v; }
    rinv[p] = 16.f / fmaxf(sqrtf(ss), EPS_);
}

// ---------------- K3: qkv = (W' @ x_b) * rinv  (bf16 out) ----------------
// tile 128x128, K=256 (BK=32), 4 waves each 64x64 via 16x16x32 MFMA
__global__ __launch_bounds__(256) void k_gemm_qkv(const ushort* __restrict__ Wp,
                                                  const float* __restrict__ x,
                                                  const float* __restrict__ rinv,
                                                  ushort* __restrict__ qkv) {
    __shared__ ushort Asub[128][40];   // [row o][k] pad->80B rows (16B aligned)
    __shared__ ushort Bsub[128][40];   // [col n][k] transposed
    const int b = blockIdx.z;
    const int row0 = blockIdx.y * 128;
    const int col0 = blockIdx.x * 128;
    const int t = threadIdx.x;
    const int l = t & 63, w = t >> 6;
    const int wr = w >> 1, wc = w & 1;
    const float* xb = x + (size_t)b * C_ * N_;
    f32x4 acc[4][4] = {};

    for (int k0 = 0; k0 < 256; k0 += 32) {
        { // stage A: 128x32 bf16 from Wp
            int r = t >> 1, ko = (t & 1) * 16;
            const uint4* src = (const uint4*)(Wp + (size_t)(row0 + r) * 256 + k0 + ko);
            *(uint4*)&Asub[r][ko]     = src[0];
            *(uint4*)&Asub[r][ko + 8] = src[1];
        }
        { // stage B: x fp32 -> bf16, transposed [n][k]; coalesced reads along n
            int nl = t & 127, kk0 = (t >> 7) * 16;
            uint pk[8];
            #pragma unroll
            for (int j = 0; j < 8; ++j) {
                ushort lo = f2bf(xb[(size_t)(k0 + kk0 + 2 * j) * N_ + col0 + nl]);
                ushort hi = f2bf(xb[(size_t)(k0 + kk0 + 2 * j + 1) * N_ + col0 + nl]);
                pk[j] = (uint)lo | ((uint)hi << 16);
            }
            *(uint4*)&Bsub[nl][kk0]     = make_uint4(pk[0], pk[1], pk[2], pk[3]);
            *(uint4*)&Bsub[nl][kk0 + 8] = make_uint4(pk[4], pk[5], pk[6], pk[7]);
        }
        __syncthreads();
        bf16x8 af[4], bfv[4];
        #pragma unroll
        for (int m = 0; m < 4; ++m)
            af[m] = *(const bf16x8*)&Asub[wr * 64 + m * 16 + (l & 15)][(l >> 4) * 8];
        #pragma unroll
        for (int n = 0; n < 4; ++n)
            bfv[n] = *(const bf16x8*)&Bsub[wc * 64 + n * 16 + (l & 15)][(l >> 4) * 8];
        #pragma unroll
        for (int m = 0; m < 4; ++m)
            #pragma unroll
            for (int n = 0; n < 4; ++n)
                acc[m][n] = __builtin_amdgcn_mfma_f32_16x16x32_bf16(af[m], bfv[n], acc[m][n], 0, 0, 0);
        __syncthreads();
    }

    ushort* qb = qkv + (size_t)b * QKV_ * N_;
    const float* rv = rinv + (size_t)b * N_;
    #pragma unroll
    for (int n = 0; n < 4; ++n) {
        int cg = col0 + wc * 64 + n * 16 + (l & 15);
        float rs = rv[cg];
        #pragma unroll
        for (int m = 0; m < 4; ++m) {
            int rbase = row0 + wr * 64 + m * 16 + (l >> 4) * 4;
            #pragma unroll
            for (int r = 0; r < 4; ++r)
                qb[(size_t)(rbase + r) * N_ + cg] = f2bf(acc[m][n][r] * rs);
        }
    }
}

// ---------------- K4: q softmax over 32 dims, in place ----------------
__global__ __launch_bounds__(256) void k_qsoftmax(ushort* __restrict__ qkv) {
    int g = blockIdx.x * 256 + threadIdx.x;
    int b = g >> 15, rem = g & 32767, h = rem >> 12, n = rem & 4095;
    ushort* qb = qkv + (size_t)b * QKV_ * N_ + (size_t)(h * 32) * N_ + n;
    float v[32]; float mx = -1e30f;
    #pragma unroll
    for (int d = 0; d < 32; ++d) { v[d] = bf2f(qb[(size_t)d * N_]); mx = fmaxf(mx, v[d]); }
    float s = 0.f;
    #pragma unroll
    for (int d = 0; d < 32; ++d) { v[d] = __expf(v[d] - mx); s += v[d]; }
    float inv = 1.f / s;
    #pragma unroll
    for (int d = 0; d < 32; ++d) qb[(size_t)d * N_] = f2bf(v[d] * inv);
}

// ---------------- K5: partial ctx = sum_n exp(k)*v, psum = sum_n exp(k) ----
// grid (bh=128, slice=4); each block covers 1024 n. No max-sub: k ~ N(0,1).
__global__ __launch_bounds__(256) void k_ctxpart(const ushort* __restrict__ qkv,
                                                 float* __restrict__ ctxp,
                                                 float* __restrict__ sums_p) {
    __shared__ float p_lds[32][66];
    __shared__ float v_lds[32][66];
    int bh = blockIdx.x, s = blockIdx.y;
    int b = bh >> 3, h = bh & 7;
    const ushort* kb = qkv + (size_t)b * QKV_ * N_ + (size_t)(256 + h * 32) * N_ + s * 1024;
    const ushort* vb = qkv + (size_t)b * QKV_ * N_ + (size_t)(512 + h * 32) * N_ + s * 1024;
    int t = threadIdx.x;
    int d = t >> 3, c8 = (t & 7) * 8;
    int e0 = (t & 7) * 4;
    float a0 = 0, a1 = 0, a2 = 0, a3 = 0, psum = 0;
    for (int nb = 0; nb < 1024; nb += 64) {
        #pragma unroll
        for (int j = 0; j < 8; ++j) {
            float pv = __expf(bf2f(kb[(size_t)d * N_ + nb + c8 + j]));
            p_lds[d][c8 + j] = pv; psum += pv;
            v_lds[d][c8 + j] = bf2f(vb[(size_t)d * N_ + nb + c8 + j]);
        }
        __syncthreads();
        #pragma unroll
        for (int j = 0; j < 64; j += 2) {
            float2 pv = *(const float2*)&p_lds[d][j];
            float2 w0 = *(const float2*)&v_lds[e0 + 0][j];
            float2 w1 = *(const float2*)&v_lds[e0 + 1][j];
            float2 w2 = *(const float2*)&v_lds[e0 + 2][j];
            float2 w3 = *(const float2*)&v_lds[e0 + 3][j];
            a0 += pv.x * w0.x + pv.y * w0.y;
            a1 += pv.x * w1.x + pv.y * w1.y;
            a2 += pv.x * w2.x + pv.y * w2.y;
            a3 += pv.x * w3.x + pv.y * w3.y;
        }
        __syncthreads();
    }
    psum += __shfl_xor(psum, 1);
    psum += __shfl_xor(psum, 2);
    psum += __shfl_xor(psum, 4);
    size_t base = (size_t)(s * 128 + bh) * 32 + d;
    if ((t & 7) == 0) sums_p[base] = psum;
    float* cp = ctxp + base * 32 + e0;
    cp[0] = a0; cp[1] = a1; cp[2] = a2; cp[3] = a3;
}

// ---------------- K6: M[b][o][hd] = SCALE * sum_e w_out[o][he]*ctx/sum ----
__global__ __launch_bounds__(256) void k_fold(const float* __restrict__ w_out,
                                              const float* __restrict__ ctxp,
                                              const float* __restrict__ sums_p,
                                              ushort* __restrict__ M) {
    int b = blockIdx.x >> 8, o = blockIdx.x & 255;
    int hd = threadIdx.x, h = hd >> 5, d = hd & 31;
    int bh = b * 8 + h;
    float stot = 0.f;
    #pragma unroll
    for (int s = 0; s < 4; ++s) stot += sums_p[(size_t)(s * 128 + bh) * 32 + d];
    const float* wr = w_out + (size_t)o * 256 + h * 32;
    float acc = 0.f;
    #pragma unroll
    for (int e = 0; e < 32; ++e) {
        float cv = 0.f;
        #pragma unroll
        for (int s = 0; s < 4; ++s)
            cv += ctxp[((size_t)(s * 128 + bh) * 32 + d) * 32 + e];
        acc += wr[e] * cv;
    }
    M[((size_t)b * 256 + o) * 256 + hd] = f2bf(acc * SCALE_ / stot);
}

// ---------------- K7: final = M @ qs ; fused +b_out, RMSNorm*g2*16, +x ----
// tile 256x128 (all rows -> full column ownership), 8 waves (4x2), BK=32
__global__ __launch_bounds__(512) void k_final(const ushort* __restrict__ M,
                                               const ushort* __restrict__ qkv,
                                               const float* __restrict__ b_out,
                                               const float* __restrict__ g2,
                                               const float* __restrict__ x,
                                               float* __restrict__ out) {
    __shared__ ushort Asub[256][40];
    __shared__ ushort Bsub[128][40];
    __shared__ float ss2[4][128];
    int b = blockIdx.y;
    int col0 = blockIdx.x * 128;
    int t = threadIdx.x, l = t & 63, w = t >> 6;
    int wr = w >> 1, wc = w & 1;
    const ushort* Mb = M + (size_t)b * 256 * 256;
    const ushort* qs = qkv + (size_t)b * QKV_ * N_;
    f32x4 acc[4][4] = {};

    for (int k0 = 0; k0 < 256; k0 += 32) {
        { // stage A: 256x32 of M
            int r = t >> 1, ko = (t & 1) * 16;
            const uint4* src = (const uint4*)(Mb + (size_t)r * 256 + k0 + ko);
            *(uint4*)&Asub[r][ko]     = src[0];
            *(uint4*)&Asub[r][ko + 8] = src[1];
        }
        { // stage B: qs 32x128 transposed -> [n][k]
            int nl = t & 127, kk0 = (t >> 7) * 8;
            uint pk[4];
            #pragma unroll
            for (int j = 0; j < 4; ++j) {
                ushort lo = qs[(size_t)(k0 + kk0 + 2 * j) * N_ + col0 + nl];
                ushort hi = qs[(size_t)(k0 + kk0 + 2 * j + 1) * N_ + col0 + nl];
                pk[j] = (uint)lo | ((uint)hi << 16);
            }
            *(uint4*)&Bsub[nl][kk0] = make_uint4(pk[0], pk[1], pk[2], pk[3]);
        }
        __syncthreads();
        bf16x8 af[4], bfv[4];
        #pragma unroll
        for (int m = 0; m < 4; ++m)
            af[m] = *(const bf16x8*)&Asub[wr * 64 + m * 16 + (l & 15)][(l >> 4) * 8];
        #pragma unroll
        for (int n = 0; n < 4; ++n)
            bfv[n] = *(const bf16x8*)&Bsub[wc * 64 + n * 16 + (l & 15)][(l >> 4) * 8];
        #pragma unroll
        for (int m = 0; m < 4; ++m)
            #pragma unroll
            for (int n = 0; n < 4; ++n)
                acc[m][n] = __builtin_amdgcn_mfma_f32_16x16x32_bf16(af[m], bfv[n], acc[m][n], 0, 0, 0);
        __syncthreads();
    }

    // epilogue: f = acc + b_out; per-column sum of squares over 256 rows
    #pragma unroll
    for (int n = 0; n < 4; ++n) {
        float local = 0.f;
        #pragma unroll
        for (int m = 0; m < 4; ++m) {
            int obase = wr * 64 + m * 16 + (l >> 4) * 4;
            #pragma unroll
            for (int r = 0; r < 4; ++r) {
                float f = acc[m][n][r] + b_out[obase + r];
                acc[m][n][r] = f;
                local += f * f;
            }
        }
        local += __shfl_xor(local, 16);
        local += __shfl_xor(local, 32);
        if ((l >> 4) == 0) ss2[wr][wc * 64 + n * 16 + (l & 15)] = local;
    }
    __syncthreads();
    const float* xb = x + (size_t)b * C_ * N_;
    float* ob = out + (size_t)b * C_ * N_;
    #pragma unroll
    for (int n = 0; n < 4; ++n) {
        int cl = wc * 64 + n * 16 + (l & 15);
        int cg = col0 + cl;
        float tot = ss2[0][cl] + ss2[1][cl] + ss2[2][cl] + ss2[3][cl];
        float rs = 16.f / fmaxf(sqrtf(tot), EPS_);
        #pragma unroll
        for (int m = 0; m < 4; ++m) {
            int obase = wr * 64 + m * 16 + (l >> 4) * 4;
            #pragma unroll
            for (int r = 0; r < 4; ++r) {
                int o = obase + r;
                ob[(size_t)o * N_ + cg] = acc[m][n][r] * rs * g2[o] + xb[(size_t)o * N_ + cg];
            }
        }
    }
}

extern "C" void kernel_launch(void* const* d_in, const int* in_sizes, int n_in,
                              void* d_out, int out_size, void* d_ws, size_t ws_size,
                              hipStream_t stream) {
    const float* x     = (const float*)d_in[0];
    const float* g1    = (const float*)d_in[1];
    const float* w_qkv = (const float*)d_in[2];
    const float* w_out = (const float*)d_in[3];
    const float* b_out = (const float*)d_in[4];
    const float* g2    = (const float*)d_in[5];
    float* out = (float*)d_out;
    char* ws = (char*)d_ws;

    float*  rinv   = (float*)(ws + 0);            //   262144 B
    ushort* Wp     = (ushort*)(ws + 262144);      //   393216 B
    float*  ctxp   = (float*)(ws + 655360);       //  2097152 B
    float*  sums_p = (float*)(ws + 2752512);      //    65536 B
    ushort* Mm     = (ushort*)(ws + 2818048);     //  2097152 B
    ushort* qkv    = (ushort*)(ws + 4915200);     // 100663296 B  (total ~100.7 MiB)

    k_prep<<<768, 256, 0, stream>>>(w_qkv, g1, Wp);
    k_rnorm<<<256, 256, 0, stream>>>(x, rinv);
    k_gemm_qkv<<<dim3(32, 6, 16), 256, 0, stream>>>(Wp, x, rinv, qkv);
    k_qsoftmax<<<2048, 256, 0, stream>>>(qkv);
    k_ctxpart<<<dim3(128, 4), 256, 0, stream>>>(qkv, ctxp, sums_p);
    k_fold<<<4096, 256, 0, stream>>>(w_out, ctxp, sums_p, Mm);
    k_final<<<dim3(32, 16), 512, 0, stream>>>(Mm, qkv, b_out, g2, x, out);
}

// Round 2
// 203.695 us; speedup vs baseline: 1.4699x; 1.4699x over previous
//
#include <hip/hip_runtime.h>
#include <math.h>

// LinearAttention: B=16, C=256, H=W=64 (N=4096), 8 heads x 32 dim.
// Pipeline: rnorm -> W'=w_qkv*g1 (bf16) -> MFMA GEMM qkv (bf16, rinv-scaled)
//  -> q-softmax in place -> partial sum(exp(k)*v), sum(exp(k)) over 4 n-slices
//  -> fold M = SCALE * w_out . ctx / sum  -> MFMA GEMM final + fused
//     (+b_out, RMSNorm*g2*16, +x) epilogue.
// R1: k_fold rewritten as block-per-(b,h) LDS kernel (was 114us latency-bound
//     uncoalesced); k_ctxpart uint4 loads; k_qsoftmax 2-wide packed.

#define B_ 16
#define C_ 256
#define N_ 4096
#define QKV_ 768
#define SCALE_ 0.17677669529663687f
#define EPS_ 1e-12f

typedef __attribute__((ext_vector_type(8))) short bf16x8;
typedef __attribute__((ext_vector_type(4))) float f32x4;

__device__ __forceinline__ ushort f2bf(float f) {
    union { float f; uint u; } x; x.f = f;
    uint r = (x.u + 0x7FFFu + ((x.u >> 16) & 1u)) >> 16;
    return (ushort)r;
}
__device__ __forceinline__ float bf2f(ushort s) {
    union { uint u; float f; } x; x.u = ((uint)s) << 16;
    return x.f;
}

// ---------------- K1: W' = w_qkv * g1 -> bf16 ----------------
__global__ __launch_bounds__(256) void k_prep(const float* __restrict__ w_qkv,
                                              const float* __restrict__ g1,
                                              ushort* __restrict__ Wp) {
    int o = blockIdx.x, c = threadIdx.x;
    Wp[(size_t)o * 256 + c] = f2bf(w_qkv[(size_t)o * 256 + c] * g1[c]);
}

// ---------------- K2: rinv[b,n] = 16 / max(||x[:,n]||, eps) ----------------
__global__ __launch_bounds__(256) void k_rnorm(const float* __restrict__ x,
                                               float* __restrict__ rinv) {
    int p = blockIdx.x * 256 + threadIdx.x;
    int b = p >> 12, n = p & 4095;
    const float* xb = x + (size_t)b * C_ * N_ + n;
    float ss = 0.f;
    #pragma unroll 8
    for (int c = 0; c < 256; ++c) { float v = xb[(size_t)c * N_]; ss += v * v; }
    rinv[p] = 16.f / fmaxf(sqrtf(ss), EPS_);
}

// ---------------- K3: qkv = (W' @ x_b) * rinv  (bf16 out) ----------------
// tile 128x128, K=256 (BK=32), 4 waves each 64x64 via 16x16x32 MFMA
__global__ __launch_bounds__(256) void k_gemm_qkv(const ushort* __restrict__ Wp,
                                                  const float* __restrict__ x,
                                                  const float* __restrict__ rinv,
                                                  ushort* __restrict__ qkv) {
    __shared__ ushort Asub[128][40];   // [row o][k] pad->80B rows (16B aligned)
    __shared__ ushort Bsub[128][40];   // [col n][k] transposed
    const int b = blockIdx.z;
    const int row0 = blockIdx.y * 128;
    const int col0 = blockIdx.x * 128;
    const int t = threadIdx.x;
    const int l = t & 63, w = t >> 6;
    const int wr = w >> 1, wc = w & 1;
    const float* xb = x + (size_t)b * C_ * N_;
    f32x4 acc[4][4] = {};

    for (int k0 = 0; k0 < 256; k0 += 32) {
        { // stage A: 128x32 bf16 from Wp
            int r = t >> 1, ko = (t & 1) * 16;
            const uint4* src = (const uint4*)(Wp + (size_t)(row0 + r) * 256 + k0 + ko);
            *(uint4*)&Asub[r][ko]     = src[0];
            *(uint4*)&Asub[r][ko + 8] = src[1];
        }
        { // stage B: x fp32 -> bf16, transposed [n][k]; coalesced reads along n
            int nl = t & 127, kk0 = (t >> 7) * 16;
            uint pk[8];
            #pragma unroll
            for (int j = 0; j < 8; ++j) {
                ushort lo = f2bf(xb[(size_t)(k0 + kk0 + 2 * j) * N_ + col0 + nl]);
                ushort hi = f2bf(xb[(size_t)(k0 + kk0 + 2 * j + 1) * N_ + col0 + nl]);
                pk[j] = (uint)lo | ((uint)hi << 16);
            }
            *(uint4*)&Bsub[nl][kk0]     = make_uint4(pk[0], pk[1], pk[2], pk[3]);
            *(uint4*)&Bsub[nl][kk0 + 8] = make_uint4(pk[4], pk[5], pk[6], pk[7]);
        }
        __syncthreads();
        bf16x8 af[4], bfv[4];
        #pragma unroll
        for (int m = 0; m < 4; ++m)
            af[m] = *(const bf16x8*)&Asub[wr * 64 + m * 16 + (l & 15)][(l >> 4) * 8];
        #pragma unroll
        for (int n = 0; n < 4; ++n)
            bfv[n] = *(const bf16x8*)&Bsub[wc * 64 + n * 16 + (l & 15)][(l >> 4) * 8];
        #pragma unroll
        for (int m = 0; m < 4; ++m)
            #pragma unroll
            for (int n = 0; n < 4; ++n)
                acc[m][n] = __builtin_amdgcn_mfma_f32_16x16x32_bf16(af[m], bfv[n], acc[m][n], 0, 0, 0);
        __syncthreads();
    }

    ushort* qb = qkv + (size_t)b * QKV_ * N_;
    const float* rv = rinv + (size_t)b * N_;
    #pragma unroll
    for (int n = 0; n < 4; ++n) {
        int cg = col0 + wc * 64 + n * 16 + (l & 15);
        float rs = rv[cg];
        #pragma unroll
        for (int m = 0; m < 4; ++m) {
            int rbase = row0 + wr * 64 + m * 16 + (l >> 4) * 4;
            #pragma unroll
            for (int r = 0; r < 4; ++r)
                qb[(size_t)(rbase + r) * N_ + cg] = f2bf(acc[m][n][r] * rs);
        }
    }
}

// ---------------- K4: q softmax over 32 dims, in place; 2 n per thread ----
__global__ __launch_bounds__(256) void k_qsoftmax(ushort* __restrict__ qkv) {
    int g = blockIdx.x * 256 + threadIdx.x;      // pair index
    int b = g >> 14, rem = g & 16383, h = rem >> 11, np = rem & 2047;
    ushort* qb = qkv + (size_t)b * QKV_ * N_ + (size_t)(h * 32) * N_ + np * 2;
    float v0[32], v1[32];
    float m0 = -1e30f, m1 = -1e30f;
    #pragma unroll
    for (int d = 0; d < 32; ++d) {
        uint u = *(const uint*)&qb[(size_t)d * N_];
        v0[d] = bf2f((ushort)(u & 0xffffu));
        v1[d] = bf2f((ushort)(u >> 16));
        m0 = fmaxf(m0, v0[d]); m1 = fmaxf(m1, v1[d]);
    }
    float s0 = 0.f, s1 = 0.f;
    #pragma unroll
    for (int d = 0; d < 32; ++d) {
        v0[d] = __expf(v0[d] - m0); s0 += v0[d];
        v1[d] = __expf(v1[d] - m1); s1 += v1[d];
    }
    float i0 = 1.f / s0, i1 = 1.f / s1;
    #pragma unroll
    for (int d = 0; d < 32; ++d) {
        uint u = (uint)f2bf(v0[d] * i0) | ((uint)f2bf(v1[d] * i1) << 16);
        *(uint*)&qb[(size_t)d * N_] = u;
    }
}

// ---------------- K5: partial ctx = sum_n exp(k)*v, psum = sum_n exp(k) ----
// grid (bh=128, slice=4); each block covers 1024 n. No max-sub: k ~ N(0,1).
__global__ __launch_bounds__(256) void k_ctxpart(const ushort* __restrict__ qkv,
                                                 float* __restrict__ ctxp,
                                                 float* __restrict__ sums_p) {
    __shared__ float p_lds[32][66];
    __shared__ float v_lds[32][66];
    int bh = blockIdx.x, s = blockIdx.y;
    int b = bh >> 3, h = bh & 7;
    const ushort* kb = qkv + (size_t)b * QKV_ * N_ + (size_t)(256 + h * 32) * N_ + s * 1024;
    const ushort* vb = qkv + (size_t)b * QKV_ * N_ + (size_t)(512 + h * 32) * N_ + s * 1024;
    int t = threadIdx.x;
    int d = t >> 3, c8 = (t & 7) * 8;
    int e0 = (t & 7) * 4;
    float a0 = 0, a1 = 0, a2 = 0, a3 = 0, psum = 0;
    for (int nb = 0; nb < 1024; nb += 64) {
        uint4 ku = *(const uint4*)&kb[(size_t)d * N_ + nb + c8];
        uint4 vu = *(const uint4*)&vb[(size_t)d * N_ + nb + c8];
        const uint* kw = (const uint*)&ku;
        const uint* vw = (const uint*)&vu;
        #pragma unroll
        for (int j = 0; j < 4; ++j) {
            float p0 = __expf(bf2f((ushort)(kw[j] & 0xffffu)));
            float p1 = __expf(bf2f((ushort)(kw[j] >> 16)));
            p_lds[d][c8 + 2 * j]     = p0;
            p_lds[d][c8 + 2 * j + 1] = p1;
            psum += p0 + p1;
            v_lds[d][c8 + 2 * j]     = bf2f((ushort)(vw[j] & 0xffffu));
            v_lds[d][c8 + 2 * j + 1] = bf2f((ushort)(vw[j] >> 16));
        }
        __syncthreads();
        #pragma unroll
        for (int j = 0; j < 64; j += 2) {
            float2 pv = *(const float2*)&p_lds[d][j];
            float2 w0 = *(const float2*)&v_lds[e0 + 0][j];
            float2 w1 = *(const float2*)&v_lds[e0 + 1][j];
            float2 w2 = *(const float2*)&v_lds[e0 + 2][j];
            float2 w3 = *(const float2*)&v_lds[e0 + 3][j];
            a0 += pv.x * w0.x + pv.y * w0.y;
            a1 += pv.x * w1.x + pv.y * w1.y;
            a2 += pv.x * w2.x + pv.y * w2.y;
            a3 += pv.x * w3.x + pv.y * w3.y;
        }
        __syncthreads();
    }
    psum += __shfl_xor(psum, 1);
    psum += __shfl_xor(psum, 2);
    psum += __shfl_xor(psum, 4);
    size_t base = (size_t)(s * 128 + bh) * 32 + d;
    if ((t & 7) == 0) sums_p[base] = psum;
    float* cp = ctxp + base * 32 + e0;
    cp[0] = a0; cp[1] = a1; cp[2] = a2; cp[3] = a3;
}

// ---------------- K6: M[b][o][h*32+d] = SCALE/stot[d] * sum_e w_out.ctx ----
// block per (b,h): reduce ctxp slices into LDS cn[e][d], then each thread
// owns output row o and does 32x32 dot products from LDS broadcasts.
__global__ __launch_bounds__(256) void k_fold(const float* __restrict__ w_out,
                                              const float* __restrict__ ctxp,
                                              const float* __restrict__ sums_p,
                                              ushort* __restrict__ M) {
    __shared__ float cn[32][33];     // [e][d]
    __shared__ float sinv[32];       // SCALE / stot[d]
    int bh = blockIdx.x;
    int b = bh >> 3, h = bh & 7;
    int t = threadIdx.x;
    if (t < 32) {
        float st = 0.f;
        #pragma unroll
        for (int s = 0; s < 4; ++s) st += sums_p[(size_t)(s * 128 + bh) * 32 + t];
        sinv[t] = SCALE_ / st;
    }
    #pragma unroll
    for (int i = t; i < 1024; i += 256) {
        int d = i >> 5, e = i & 31;
        float cv = 0.f;
        #pragma unroll
        for (int s = 0; s < 4; ++s)
            cv += ctxp[((size_t)(s * 128 + bh) * 32 + d) * 32 + e];
        cn[e][d] = cv;
    }
    __syncthreads();
    float wreg[32];
    const float* wr = w_out + (size_t)t * 256 + h * 32;
    #pragma unroll
    for (int e = 0; e < 32; e += 4) {
        float4 wv = *(const float4*)&wr[e];
        wreg[e] = wv.x; wreg[e + 1] = wv.y; wreg[e + 2] = wv.z; wreg[e + 3] = wv.w;
    }
    float acc[32] = {};
    #pragma unroll
    for (int e = 0; e < 32; ++e) {
        float we = wreg[e];
        #pragma unroll
        for (int d = 0; d < 32; ++d) acc[d] += we * cn[e][d];
    }
    ushort* Mrow = M + ((size_t)b * 256 + t) * 256 + h * 32;
    #pragma unroll
    for (int d = 0; d < 32; ++d) Mrow[d] = f2bf(acc[d] * sinv[d]);
}

// ---------------- K7: final = M @ qs ; fused +b_out, RMSNorm*g2*16, +x ----
// tile 256x128 (all rows -> full column ownership), 8 waves (4x2), BK=32
__global__ __launch_bounds__(512) void k_final(const ushort* __restrict__ M,
                                               const ushort* __restrict__ qkv,
                                               const float* __restrict__ b_out,
                                               const float* __restrict__ g2,
                                               const float* __restrict__ x,
                                               float* __restrict__ out) {
    __shared__ ushort Asub[256][40];
    __shared__ ushort Bsub[128][40];
    __shared__ float ss2[4][128];
    int b = blockIdx.y;
    int col0 = blockIdx.x * 128;
    int t = threadIdx.x, l = t & 63, w = t >> 6;
    int wr = w >> 1, wc = w & 1;
    const ushort* Mb = M + (size_t)b * 256 * 256;
    const ushort* qs = qkv + (size_t)b * QKV_ * N_;
    f32x4 acc[4][4] = {};

    for (int k0 = 0; k0 < 256; k0 += 32) {
        { // stage A: 256x32 of M
            int r = t >> 1, ko = (t & 1) * 16;
            const uint4* src = (const uint4*)(Mb + (size_t)r * 256 + k0 + ko);
            *(uint4*)&Asub[r][ko]     = src[0];
            *(uint4*)&Asub[r][ko + 8] = src[1];
        }
        { // stage B: qs 32x128 transposed -> [n][k]
            int nl = t & 127, kk0 = (t >> 7) * 8;
            uint pk[4];
            #pragma unroll
            for (int j = 0; j < 4; ++j) {
                ushort lo = qs[(size_t)(k0 + kk0 + 2 * j) * N_ + col0 + nl];
                ushort hi = qs[(size_t)(k0 + kk0 + 2 * j + 1) * N_ + col0 + nl];
                pk[j] = (uint)lo | ((uint)hi << 16);
            }
            *(uint4*)&Bsub[nl][kk0] = make_uint4(pk[0], pk[1], pk[2], pk[3]);
        }
        __syncthreads();
        bf16x8 af[4], bfv[4];
        #pragma unroll
        for (int m = 0; m < 4; ++m)
            af[m] = *(const bf16x8*)&Asub[wr * 64 + m * 16 + (l & 15)][(l >> 4) * 8];
        #pragma unroll
        for (int n = 0; n < 4; ++n)
            bfv[n] = *(const bf16x8*)&Bsub[wc * 64 + n * 16 + (l & 15)][(l >> 4) * 8];
        #pragma unroll
        for (int m = 0; m < 4; ++m)
            #pragma unroll
            for (int n = 0; n < 4; ++n)
                acc[m][n] = __builtin_amdgcn_mfma_f32_16x16x32_bf16(af[m], bfv[n], acc[m][n], 0, 0, 0);
        __syncthreads();
    }

    // epilogue: f = acc + b_out; per-column sum of squares over 256 rows
    #pragma unroll
    for (int n = 0; n < 4; ++n) {
        float local = 0.f;
        #pragma unroll
        for (int m = 0; m < 4; ++m) {
            int obase = wr * 64 + m * 16 + (l >> 4) * 4;
            #pragma unroll
            for (int r = 0; r < 4; ++r) {
                float f = acc[m][n][r] + b_out[obase + r];
                acc[m][n][r] = f;
                local += f * f;
            }
        }
        local += __shfl_xor(local, 16);
        local += __shfl_xor(local, 32);
        if ((l >> 4) == 0) ss2[wr][wc * 64 + n * 16 + (l & 15)] = local;
    }
    __syncthreads();
    const float* xb = x + (size_t)b * C_ * N_;
    float* ob = out + (size_t)b * C_ * N_;
    #pragma unroll
    for (int n = 0; n < 4; ++n) {
        int cl = wc * 64 + n * 16 + (l & 15);
        int cg = col0 + cl;
        float tot = ss2[0][cl] + ss2[1][cl] + ss2[2][cl] + ss2[3][cl];
        float rs = 16.f / fmaxf(sqrtf(tot), EPS_);
        #pragma unroll
        for (int m = 0; m < 4; ++m) {
            int obase = wr * 64 + m * 16 + (l >> 4) * 4;
            #pragma unroll
            for (int r = 0; r < 4; ++r) {
                int o = obase + r;
                ob[(size_t)o * N_ + cg] = acc[m][n][r] * rs * g2[o] + xb[(size_t)o * N_ + cg];
            }
        }
    }
}

extern "C" void kernel_launch(void* const* d_in, const int* in_sizes, int n_in,
                              void* d_out, int out_size, void* d_ws, size_t ws_size,
                              hipStream_t stream) {
    const float* x     = (const float*)d_in[0];
    const float* g1    = (const float*)d_in[1];
    const float* w_qkv = (const float*)d_in[2];
    const float* w_out = (const float*)d_in[3];
    const float* b_out = (const float*)d_in[4];
    const float* g2    = (const float*)d_in[5];
    float* out = (float*)d_out;
    char* ws = (char*)d_ws;

    float*  rinv   = (float*)(ws + 0);            //   262144 B
    ushort* Wp     = (ushort*)(ws + 262144);      //   393216 B
    float*  ctxp   = (float*)(ws + 655360);       //  2097152 B
    float*  sums_p = (float*)(ws + 2752512);      //    65536 B
    ushort* Mm     = (ushort*)(ws + 2818048);     //  2097152 B
    ushort* qkv    = (ushort*)(ws + 4915200);     // 100663296 B  (total ~100.7 MiB)

    k_prep<<<768, 256, 0, stream>>>(w_qkv, g1, Wp);
    k_rnorm<<<256, 256, 0, stream>>>(x, rinv);
    k_gemm_qkv<<<dim3(32, 6, 16), 256, 0, stream>>>(Wp, x, rinv, qkv);
    k_qsoftmax<<<1024, 256, 0, stream>>>(qkv);
    k_ctxpart<<<dim3(128, 4), 256, 0, stream>>>(qkv, ctxp, sums_p);
    k_fold<<<128, 256, 0, stream>>>(w_out, ctxp, sums_p, Mm);
    k_final<<<dim3(32, 16), 512, 0, stream>>>(Mm, qkv, b_out, g2, x, out);
}

// Round 3
// 150.070 us; speedup vs baseline: 1.9952x; 1.3573x over previous
//
#include <hip/hip_runtime.h>
#include <math.h>

// LinearAttention: B=16, C=256, H=W=64 (N=4096), 8 heads x 32 dim.
// Pipeline: rnorm -> W'=w_qkv*g1 (bf16) -> MFMA GEMM qkv (bf16, rinv-scaled,
//   fused q-softmax epilogue) -> MFMA partial sum(exp(k)*v), sum(exp(k))
//  -> fold M = SCALE * w_out . ctx / sum  -> MFMA GEMM final + fused
//     (+b_out, RMSNorm*g2*16, +x) epilogue.
// R1: k_fold -> block-per-(b,h) LDS kernel (was 114us latency-bound).
// R2: k_ctxpart -> MFMA fragments straight from global (was 65us LDS-bound
//     with 9.4M bank conflicts); q-softmax fused into k_gemm_qkv epilogue.

#define B_ 16
#define C_ 256
#define N_ 4096
#define QKV_ 768
#define SCALE_ 0.17677669529663687f
#define EPS_ 1e-12f

typedef __attribute__((ext_vector_type(8))) short bf16x8;
typedef __attribute__((ext_vector_type(4))) float f32x4;

__device__ __forceinline__ ushort f2bf(float f) {
    union { float f; uint u; } x; x.f = f;
    uint r = (x.u + 0x7FFFu + ((x.u >> 16) & 1u)) >> 16;
    return (ushort)r;
}
__device__ __forceinline__ float bf2f(ushort s) {
    union { uint u; float f; } x; x.u = ((uint)s) << 16;
    return x.f;
}

// ---------------- K1: W' = w_qkv * g1 -> bf16 ----------------
__global__ __launch_bounds__(256) void k_prep(const float* __restrict__ w_qkv,
                                              const float* __restrict__ g1,
                                              ushort* __restrict__ Wp) {
    int o = blockIdx.x, c = threadIdx.x;
    Wp[(size_t)o * 256 + c] = f2bf(w_qkv[(size_t)o * 256 + c] * g1[c]);
}

// ---------------- K2: rinv[b,n] = 16 / max(||x[:,n]||, eps) ----------------
__global__ __launch_bounds__(256) void k_rnorm(const float* __restrict__ x,
                                               float* __restrict__ rinv) {
    int p = blockIdx.x * 256 + threadIdx.x;
    int b = p >> 12, n = p & 4095;
    const float* xb = x + (size_t)b * C_ * N_ + n;
    float ss = 0.f;
    #pragma unroll 8
    for (int c = 0; c < 256; ++c) { float v = xb[(size_t)c * N_]; ss += v * v; }
    rinv[p] = 16.f / fmaxf(sqrtf(ss), EPS_);
}

// ---------------- K3: qkv = (W' @ x_b) * rinv  (bf16 out) ----------------
// tile 128x128, K=256 (BK=32), 4 waves each 64x64 via 16x16x32 MFMA.
// q row-tiles (row0<256) apply per-head softmax over d in the epilogue.
__global__ __launch_bounds__(256) void k_gemm_qkv(const ushort* __restrict__ Wp,
                                                  const float* __restrict__ x,
                                                  const float* __restrict__ rinv,
                                                  ushort* __restrict__ qkv) {
    __shared__ ushort Asub[128][40];   // [row o][k]
    __shared__ ushort Bsub[128][40];   // [col n][k] transposed
    const int b = blockIdx.z;
    const int row0 = blockIdx.y * 128;
    const int col0 = blockIdx.x * 128;
    const int t = threadIdx.x;
    const int l = t & 63, w = t >> 6;
    const int wr = w >> 1, wc = w & 1;
    const float* xb = x + (size_t)b * C_ * N_;
    f32x4 acc[4][4] = {};

    for (int k0 = 0; k0 < 256; k0 += 32) {
        { // stage A: 128x32 bf16 from Wp
            int r = t >> 1, ko = (t & 1) * 16;
            const uint4* src = (const uint4*)(Wp + (size_t)(row0 + r) * 256 + k0 + ko);
            *(uint4*)&Asub[r][ko]     = src[0];
            *(uint4*)&Asub[r][ko + 8] = src[1];
        }
        { // stage B: x fp32 -> bf16, transposed [n][k]
            int nl = t & 127, kk0 = (t >> 7) * 16;
            uint pk[8];
            #pragma unroll
            for (int j = 0; j < 8; ++j) {
                ushort lo = f2bf(xb[(size_t)(k0 + kk0 + 2 * j) * N_ + col0 + nl]);
                ushort hi = f2bf(xb[(size_t)(k0 + kk0 + 2 * j + 1) * N_ + col0 + nl]);
                pk[j] = (uint)lo | ((uint)hi << 16);
            }
            *(uint4*)&Bsub[nl][kk0]     = make_uint4(pk[0], pk[1], pk[2], pk[3]);
            *(uint4*)&Bsub[nl][kk0 + 8] = make_uint4(pk[4], pk[5], pk[6], pk[7]);
        }
        __syncthreads();
        bf16x8 af[4], bfv[4];
        #pragma unroll
        for (int m = 0; m < 4; ++m)
            af[m] = *(const bf16x8*)&Asub[wr * 64 + m * 16 + (l & 15)][(l >> 4) * 8];
        #pragma unroll
        for (int n = 0; n < 4; ++n)
            bfv[n] = *(const bf16x8*)&Bsub[wc * 64 + n * 16 + (l & 15)][(l >> 4) * 8];
        #pragma unroll
        for (int m = 0; m < 4; ++m)
            #pragma unroll
            for (int n = 0; n < 4; ++n)
                acc[m][n] = __builtin_amdgcn_mfma_f32_16x16x32_bf16(af[m], bfv[n], acc[m][n], 0, 0, 0);
        __syncthreads();
    }

    ushort* qb = qkv + (size_t)b * QKV_ * N_;
    const float* rv = rinv + (size_t)b * N_;
    const bool isq = (row0 < 256);   // rows 0..255 are q -> fused softmax over d
    #pragma unroll
    for (int n = 0; n < 4; ++n) {
        int cg = col0 + wc * 64 + n * 16 + (l & 15);
        float rs = rv[cg];
        float f[4][4];
        #pragma unroll
        for (int m = 0; m < 4; ++m)
            #pragma unroll
            for (int r = 0; r < 4; ++r) f[m][r] = acc[m][n][r] * rs;
        if (isq) {
            // wave rows wr*64: m=0,1 -> one head (32 d), m=2,3 -> next head
            float mxA = -1e30f, mxB = -1e30f;
            #pragma unroll
            for (int r = 0; r < 4; ++r) {
                mxA = fmaxf(mxA, fmaxf(f[0][r], f[1][r]));
                mxB = fmaxf(mxB, fmaxf(f[2][r], f[3][r]));
            }
            mxA = fmaxf(mxA, __shfl_xor(mxA, 16));
            mxA = fmaxf(mxA, __shfl_xor(mxA, 32));
            mxB = fmaxf(mxB, __shfl_xor(mxB, 16));
            mxB = fmaxf(mxB, __shfl_xor(mxB, 32));
            float sA = 0.f, sB = 0.f;
            #pragma unroll
            for (int r = 0; r < 4; ++r) {
                f[0][r] = __expf(f[0][r] - mxA); sA += f[0][r];
                f[1][r] = __expf(f[1][r] - mxA); sA += f[1][r];
                f[2][r] = __expf(f[2][r] - mxB); sB += f[2][r];
                f[3][r] = __expf(f[3][r] - mxB); sB += f[3][r];
            }
            sA += __shfl_xor(sA, 16); sA += __shfl_xor(sA, 32);
            sB += __shfl_xor(sB, 16); sB += __shfl_xor(sB, 32);
            float iA = 1.f / sA, iB = 1.f / sB;
            #pragma unroll
            for (int r = 0; r < 4; ++r) {
                f[0][r] *= iA; f[1][r] *= iA;
                f[2][r] *= iB; f[3][r] *= iB;
            }
        }
        #pragma unroll
        for (int m = 0; m < 4; ++m) {
            int rbase = row0 + wr * 64 + m * 16 + (l >> 4) * 4;
            #pragma unroll
            for (int r = 0; r < 4; ++r)
                qb[(size_t)(rbase + r) * N_ + cg] = f2bf(f[m][r]);
        }
    }
}

// ---------------- K5: partial ctx = P @ V^T via MFMA, psum = P @ 1 --------
// grid (bh=128, slice=4); block 256 = 4 waves, wave covers 256 n (8 K-iters).
// Fragments loaded straight from global; exp in-register; LDS only for the
// final 4-wave reduction. No max-sub: k ~ N(0,1), exp safe in fp32.
__global__ __launch_bounds__(256) void k_ctxpart(const ushort* __restrict__ qkv,
                                                 float* __restrict__ ctxp,
                                                 float* __restrict__ sums_p) {
    __shared__ float red[4][32][33];   // [wave][d][e] padded
    __shared__ float redp[4][32];
    int bh = blockIdx.x, s = blockIdx.y;
    int b = bh >> 3, h = bh & 7;
    int t = threadIdx.x, l = t & 63, w = t >> 6;
    const ushort* kb = qkv + (size_t)b * QKV_ * N_ + (size_t)(256 + h * 32) * N_;
    const ushort* vb = qkv + (size_t)b * QKV_ * N_ + (size_t)(512 + h * 32) * N_;
    const int n0base = s * 1024 + w * 256;
    const int row = l & 15, grp = l >> 4;
    f32x4 acc[2][2] = {};
    float psA = 0.f, psB = 0.f;

    for (int it = 0; it < 8; ++it) {
        int n0 = n0base + it * 32 + grp * 8;
        bf16x8 k0 = *(const bf16x8*)&kb[(size_t)row * N_ + n0];
        bf16x8 k1 = *(const bf16x8*)&kb[(size_t)(row + 16) * N_ + n0];
        bf16x8 v0 = *(const bf16x8*)&vb[(size_t)row * N_ + n0];
        bf16x8 v1 = *(const bf16x8*)&vb[(size_t)(row + 16) * N_ + n0];
        bf16x8 p0, p1;
        #pragma unroll
        for (int j = 0; j < 8; ++j) {
            ushort r0 = f2bf(__expf(bf2f((ushort)k0[j])));
            ushort r1 = f2bf(__expf(bf2f((ushort)k1[j])));
            p0[j] = (short)r0; p1[j] = (short)r1;
            psA += bf2f(r0); psB += bf2f(r1);
        }
        acc[0][0] = __builtin_amdgcn_mfma_f32_16x16x32_bf16(p0, v0, acc[0][0], 0, 0, 0);
        acc[0][1] = __builtin_amdgcn_mfma_f32_16x16x32_bf16(p0, v1, acc[0][1], 0, 0, 0);
        acc[1][0] = __builtin_amdgcn_mfma_f32_16x16x32_bf16(p1, v0, acc[1][0], 0, 0, 0);
        acc[1][1] = __builtin_amdgcn_mfma_f32_16x16x32_bf16(p1, v1, acc[1][1], 0, 0, 0);
    }

    psA += __shfl_xor(psA, 16); psA += __shfl_xor(psA, 32);
    psB += __shfl_xor(psB, 16); psB += __shfl_xor(psB, 32);
    // D layout: ctx[d = mi*16 + grp*4 + r][e = ni*16 + row]
    #pragma unroll
    for (int mi = 0; mi < 2; ++mi)
        #pragma unroll
        for (int ni = 0; ni < 2; ++ni)
            #pragma unroll
            for (int r = 0; r < 4; ++r)
                red[w][mi * 16 + grp * 4 + r][ni * 16 + row] = acc[mi][ni][r];
    if (l < 16) { redp[w][l] = psA; redp[w][16 + l] = psB; }
    __syncthreads();

    size_t base = (size_t)(s * 128 + bh) * 32;
    #pragma unroll
    for (int i = t; i < 1024; i += 256) {
        int d = i >> 5, e = i & 31;
        ctxp[(base + d) * 32 + e] =
            red[0][d][e] + red[1][d][e] + red[2][d][e] + red[3][d][e];
    }
    if (t < 32)
        sums_p[base + t] = redp[0][t] + redp[1][t] + redp[2][t] + redp[3][t];
}

// ---------------- K6: M[b][o][h*32+d] = SCALE/stot[d] * sum_e w_out.ctx ----
__global__ __launch_bounds__(256) void k_fold(const float* __restrict__ w_out,
                                              const float* __restrict__ ctxp,
                                              const float* __restrict__ sums_p,
                                              ushort* __restrict__ M) {
    __shared__ float cn[32][33];     // [e][d]
    __shared__ float sinv[32];       // SCALE / stot[d]
    int bh = blockIdx.x;
    int b = bh >> 3, h = bh & 7;
    int t = threadIdx.x;
    if (t < 32) {
        float st = 0.f;
        #pragma unroll
        for (int s = 0; s < 4; ++s) st += sums_p[(size_t)(s * 128 + bh) * 32 + t];
        sinv[t] = SCALE_ / st;
    }
    #pragma unroll
    for (int i = t; i < 1024; i += 256) {
        int d = i >> 5, e = i & 31;
        float cv = 0.f;
        #pragma unroll
        for (int s = 0; s < 4; ++s)
            cv += ctxp[((size_t)(s * 128 + bh) * 32 + d) * 32 + e];
        cn[e][d] = cv;
    }
    __syncthreads();
    float wreg[32];
    const float* wr = w_out + (size_t)t * 256 + h * 32;
    #pragma unroll
    for (int e = 0; e < 32; e += 4) {
        float4 wv = *(const float4*)&wr[e];
        wreg[e] = wv.x; wreg[e + 1] = wv.y; wreg[e + 2] = wv.z; wreg[e + 3] = wv.w;
    }
    float acc[32] = {};
    #pragma unroll
    for (int e = 0; e < 32; ++e) {
        float we = wreg[e];
        #pragma unroll
        for (int d = 0; d < 32; ++d) acc[d] += we * cn[e][d];
    }
    ushort* Mrow = M + ((size_t)b * 256 + t) * 256 + h * 32;
    #pragma unroll
    for (int d = 0; d < 32; ++d) Mrow[d] = f2bf(acc[d] * sinv[d]);
}

// ---------------- K7: final = M @ qs ; fused +b_out, RMSNorm*g2*16, +x ----
// tile 256x128 (all rows -> full column ownership), 8 waves (4x2), BK=32
__global__ __launch_bounds__(512) void k_final(const ushort* __restrict__ M,
                                               const ushort* __restrict__ qkv,
                                               const float* __restrict__ b_out,
                                               const float* __restrict__ g2,
                                               const float* __restrict__ x,
                                               float* __restrict__ out) {
    __shared__ ushort Asub[256][40];
    __shared__ ushort Bsub[128][40];
    __shared__ float ss2[4][128];
    int b = blockIdx.y;
    int col0 = blockIdx.x * 128;
    int t = threadIdx.x, l = t & 63, w = t >> 6;
    int wr = w >> 1, wc = w & 1;
    const ushort* Mb = M + (size_t)b * 256 * 256;
    const ushort* qs = qkv + (size_t)b * QKV_ * N_;
    f32x4 acc[4][4] = {};

    for (int k0 = 0; k0 < 256; k0 += 32) {
        { // stage A: 256x32 of M
            int r = t >> 1, ko = (t & 1) * 16;
            const uint4* src = (const uint4*)(Mb + (size_t)r * 256 + k0 + ko);
            *(uint4*)&Asub[r][ko]     = src[0];
            *(uint4*)&Asub[r][ko + 8] = src[1];
        }
        { // stage B: qs 32x128 transposed -> [n][k]
            int nl = t & 127, kk0 = (t >> 7) * 8;
            uint pk[4];
            #pragma unroll
            for (int j = 0; j < 4; ++j) {
                ushort lo = qs[(size_t)(k0 + kk0 + 2 * j) * N_ + col0 + nl];
                ushort hi = qs[(size_t)(k0 + kk0 + 2 * j + 1) * N_ + col0 + nl];
                pk[j] = (uint)lo | ((uint)hi << 16);
            }
            *(uint4*)&Bsub[nl][kk0] = make_uint4(pk[0], pk[1], pk[2], pk[3]);
        }
        __syncthreads();
        bf16x8 af[4], bfv[4];
        #pragma unroll
        for (int m = 0; m < 4; ++m)
            af[m] = *(const bf16x8*)&Asub[wr * 64 + m * 16 + (l & 15)][(l >> 4) * 8];
        #pragma unroll
        for (int n = 0; n < 4; ++n)
            bfv[n] = *(const bf16x8*)&Bsub[wc * 64 + n * 16 + (l & 15)][(l >> 4) * 8];
        #pragma unroll
        for (int m = 0; m < 4; ++m)
            #pragma unroll
            for (int n = 0; n < 4; ++n)
                acc[m][n] = __builtin_amdgcn_mfma_f32_16x16x32_bf16(af[m], bfv[n], acc[m][n], 0, 0, 0);
        __syncthreads();
    }

    // epilogue: f = acc + b_out; per-column sum of squares over 256 rows
    #pragma unroll
    for (int n = 0; n < 4; ++n) {
        float local = 0.f;
        #pragma unroll
        for (int m = 0; m < 4; ++m) {
            int obase = wr * 64 + m * 16 + (l >> 4) * 4;
            #pragma unroll
            for (int r = 0; r < 4; ++r) {
                float f = acc[m][n][r] + b_out[obase + r];
                acc[m][n][r] = f;
                local += f * f;
            }
        }
        local += __shfl_xor(local, 16);
        local += __shfl_xor(local, 32);
        if ((l >> 4) == 0) ss2[wr][wc * 64 + n * 16 + (l & 15)] = local;
    }
    __syncthreads();
    const float* xb = x + (size_t)b * C_ * N_;
    float* ob = out + (size_t)b * C_ * N_;
    #pragma unroll
    for (int n = 0; n < 4; ++n) {
        int cl = wc * 64 + n * 16 + (l & 15);
        int cg = col0 + cl;
        float tot = ss2[0][cl] + ss2[1][cl] + ss2[2][cl] + ss2[3][cl];
        float rs = 16.f / fmaxf(sqrtf(tot), EPS_);
        #pragma unroll
        for (int m = 0; m < 4; ++m) {
            int obase = wr * 64 + m * 16 + (l >> 4) * 4;
            #pragma unroll
            for (int r = 0; r < 4; ++r) {
                int o = obase + r;
                ob[(size_t)o * N_ + cg] = acc[m][n][r] * rs * g2[o] + xb[(size_t)o * N_ + cg];
            }
        }
    }
}

extern "C" void kernel_launch(void* const* d_in, const int* in_sizes, int n_in,
                              void* d_out, int out_size, void* d_ws, size_t ws_size,
                              hipStream_t stream) {
    const float* x     = (const float*)d_in[0];
    const float* g1    = (const float*)d_in[1];
    const float* w_qkv = (const float*)d_in[2];
    const float* w_out = (const float*)d_in[3];
    const float* b_out = (const float*)d_in[4];
    const float* g2    = (const float*)d_in[5];
    float* out = (float*)d_out;
    char* ws = (char*)d_ws;

    float*  rinv   = (float*)(ws + 0);            //   262144 B
    ushort* Wp     = (ushort*)(ws + 262144);      //   393216 B
    float*  ctxp   = (float*)(ws + 655360);       //  2097152 B
    float*  sums_p = (float*)(ws + 2752512);      //    65536 B
    ushort* Mm     = (ushort*)(ws + 2818048);     //  2097152 B
    ushort* qkv    = (ushort*)(ws + 4915200);     // 100663296 B  (total ~100.7 MiB)

    k_prep<<<768, 256, 0, stream>>>(w_qkv, g1, Wp);
    k_rnorm<<<256, 256, 0, stream>>>(x, rinv);
    k_gemm_qkv<<<dim3(32, 6, 16), 256, 0, stream>>>(Wp, x, rinv, qkv);
    k_ctxpart<<<dim3(128, 4), 256, 0, stream>>>(qkv, ctxp, sums_p);
    k_fold<<<128, 256, 0, stream>>>(w_out, ctxp, sums_p, Mm);
    k_final<<<dim3(32, 16), 512, 0, stream>>>(Mm, qkv, b_out, g2, x, out);
}